// Round 14
// baseline (224.013 us; speedup 1.0000x reference)
//
#include <hip/hip_runtime.h>

#define N_NODES 50000
#define E_EDGES 800000
#define FEAT    128
#define KORD    3
#define BN_EPS  1e-5f
#define NB1     49          // ceil(50000/1024) scan blocks
#define NBUK    49          // coarse buckets (dst >> 10)
#define BCAP    20480       // bucket capacity
#define NSHARD  16          // BN-stats atomic shards
#define NWB_BLKS 12500      // (N_NODES*64)/256 one-wave-per-node blocks

typedef __fp16 f16x2 __attribute__((ext_vector_type(2)));
typedef __fp16 f16x8 __attribute__((ext_vector_type(8)));
typedef __attribute__((ext_vector_type(4))) float f32x4;

__device__ __forceinline__ unsigned h2u(f16x2 h) { union { f16x2 h; unsigned u; } c; c.h = h; return c.u; }
__device__ __forceinline__ f16x2 u2h(unsigned u) { union { unsigned u; f16x2 h; } c; c.u = u; return c.h; }

// ---- per node: feature->f16, pack {coords, g=attW@f}; tail blocks: fold
//      GT[o][k*128+i] = sum_j L[k][i][j]*W[o][j]  (gprep merged in) ----
__global__ void g_cast(const float* __restrict__ feat,
                       const float* __restrict__ coords,
                       const float* __restrict__ attW,
                       const float* __restrict__ W,
                       const float* __restrict__ L,
                       __fp16* __restrict__ fh,
                       float4* __restrict__ pk,
                       __fp16* __restrict__ GT) {
    __shared__ float wrow[FEAT];
    if (blockIdx.x >= NWB_BLKS) {            // gprep tail blocks (128)
        const int o = blockIdx.x - NWB_BLKS;
        const int i = threadIdx.x;
        if (i < FEAT) wrow[i] = W[o * FEAT + i];
        __syncthreads();
        if (i < FEAT) {
            #pragma unroll
            for (int k = 0; k < KORD; ++k) {
                const float* lp = L + ((size_t)k * FEAT + i) * FEAT;
                float acc = 0.f;
                #pragma unroll 8
                for (int j = 0; j < FEAT; ++j) acc = fmaf(lp[j], wrow[j], acc);
                GT[(size_t)o * 384 + k * FEAT + i] = (__fp16)acc;
            }
        }
        return;
    }
    const int node = (blockIdx.x * blockDim.x + threadIdx.x) >> 6;
    const int lane = threadIdx.x & 63;
    if (node >= N_NODES) return;
    const float2 f = *(const float2*)(feat + (size_t)node * FEAT + lane * 2);
    *(f16x2*)(fh + (size_t)node * FEAT + lane * 2) = __builtin_amdgcn_cvt_pkrtz(f.x, f.y);
    float gg[3];
    #pragma unroll
    for (int j = 0; j < 3; ++j) {
        float p = f.x * attW[j * FEAT + lane * 2] + f.y * attW[j * FEAT + lane * 2 + 1];
        #pragma unroll
        for (int off = 32; off; off >>= 1) p += __shfl_xor(p, off);
        gg[j] = p;
    }
    if (lane == 0) {
        const float c0 = coords[node * 3 + 0], c1 = coords[node * 3 + 1], c2 = coords[node * 3 + 2];
        pk[2 * node]     = make_float4(c0, c1, c2, gg[0]);
        pk[2 * node + 1] = make_float4(gg[1], gg[2], 0.f, 0.f);
    }
}

// ============ CSR build ============
__global__ __launch_bounds__(256)
void bucketA(const int* __restrict__ src, const int* __restrict__ dst,
             const int* __restrict__ order,
             int* __restrict__ cnt, int* __restrict__ gcur, int2* __restrict__ bbuf) {
    __shared__ int lcnt[NBUK];
    __shared__ int lbase[NBUK];
    const int tid = threadIdx.x;
    if (tid < NBUK) lcnt[tid] = 0;
    __syncthreads();
    const int e0 = blockIdx.x * 2048;
    int b[8], r[8], so[8], dd[8];
    #pragma unroll
    for (int i = 0; i < 8; ++i) {
        const int e = e0 + i * 256 + tid;
        if (e < E_EDGES) {
            dd[i] = dst[e];
            so[i] = (order[e] << 16) | src[e];
            b[i] = dd[i] >> 10;
            r[i] = atomicAdd(&lcnt[b[i]], 1);
            atomicAdd(cnt + dd[i], 1);
        } else b[i] = -1;
    }
    __syncthreads();
    if (tid < NBUK) lbase[tid] = atomicAdd(&gcur[tid], lcnt[tid]);
    __syncthreads();
    #pragma unroll
    for (int i = 0; i < 8; ++i)
        if (b[i] >= 0)
            bbuf[(size_t)b[i] * BCAP + lbase[b[i]] + r[i]] = make_int2(so[i], dd[i]);
}

__global__ __launch_bounds__(256)
void scan1(const int* __restrict__ cnt, int* __restrict__ rowptr, int* __restrict__ bsum) {
    __shared__ int lds[256];
    const int b = blockIdx.x, t = threadIdx.x;
    const int base = b * 1024 + t * 4;
    int v[4];
    #pragma unroll
    for (int i = 0; i < 4; ++i) v[i] = (base + i < N_NODES) ? cnt[base + i] : 0;
    lds[t] = v[0] + v[1] + v[2] + v[3];
    __syncthreads();
    for (int off = 1; off < 256; off <<= 1) {
        const int u = (t >= off) ? lds[t - off] : 0;
        __syncthreads();
        lds[t] += u;
        __syncthreads();
    }
    int excl = t ? lds[t - 1] : 0;
    if (t == 255) bsum[b] = lds[255];
    #pragma unroll
    for (int i = 0; i < 4; ++i) {
        if (base + i < N_NODES) rowptr[base + i] = excl;
        excl += v[i];
    }
}

// ---- scan3 (scan2 folded in: wave 0 rescans the 49 block sums) ----
__global__ void scan3(int* __restrict__ rowptr, int* __restrict__ cursor,
                      const int* __restrict__ bsum) {
    __shared__ int boff_s[64];
    const int t = threadIdx.x;
    if (t < 64) {
        const int v = (t < NB1) ? bsum[t] : 0;
        int incl = v;
        #pragma unroll
        for (int off = 1; off < 64; off <<= 1) {
            const int u = __shfl_up(incl, off);
            if (t >= off) incl += u;
        }
        boff_s[t] = incl - v;
    }
    __syncthreads();
    const int i = blockIdx.x * 256 + t;
    if (i < N_NODES) {
        const int v = rowptr[i] + boff_s[i >> 10];
        rowptr[i] = v;
        cursor[i] = v;
    }
    if (i == 0) rowptr[N_NODES] = E_EDGES;
}

__global__ void bucketB(const int* __restrict__ gcur, const int2* __restrict__ bbuf,
                        int* __restrict__ cursor, int* __restrict__ sord_p) {
    const int b = blockIdx.x >> 3;
    const int seg = blockIdx.x & 7;
    const int n = gcur[b];
    const int lo = (int)((long)n * seg / 8), hi = (int)((long)n * (seg + 1) / 8);
    for (int i = lo + (int)threadIdx.x; i < hi; i += 256) {
        const int2 ent = bbuf[(size_t)b * BCAP + i];
        const int pos = atomicAdd(cursor + ent.y, 1);
        sord_p[pos] = ent.x;
    }
}

// ---- fused edge-att + segment softmax + per-order gather-aggregate ----
__global__ void segagg(const float4* __restrict__ pk,
                       const int* __restrict__ sord_p,
                       const int* __restrict__ rowptr,
                       const __fp16* __restrict__ fh,
                       __fp16* __restrict__ agg) {
    __shared__ uint4 stash[4][64];
    const int node = (blockIdx.x * blockDim.x + threadIdx.x) >> 6;
    const int lane = threadIdx.x & 63;
    const int wid  = threadIdx.x >> 6;
    if (node >= N_NODES) return;
    const int beg = rowptr[node], end = rowptr[node + 1];
    const float4 b0 = pk[2 * node];

    float att0 = -1e30f, inv0 = 0.f; int sol0 = 0;
    float m = -1e30f, s = 0.f;
    int nch = 0;
    for (int cb = beg; cb < end; cb += 64, ++nch) {
        const int p = cb + lane;
        float a = -1e30f, iv = 0.f; int so = 0;
        if (p < end) {
            so = sord_p[p];
            const int sn = so & 0xFFFF;
            const float4 a0 = pk[2 * sn], a1 = pk[2 * sn + 1];
            const float dx = a0.x - b0.x, dy = a0.y - b0.y, dz = a0.z - b0.z;
            a = dx * a0.w + dy * a1.x + dz * a1.y;
            iv = 1.f / (dx * dx + dy * dy + dz * dz + 1.f);
        }
        if (nch == 0) { att0 = a; inv0 = iv; sol0 = so; }
        const float mn = fmaxf(m, a);
        s = s * __expf(m - mn) + ((p < end) ? __expf(a - mn) : 0.f);
        m = mn;
    }
    #pragma unroll
    for (int off = 32; off; off >>= 1) {
        const float mo = __shfl_xor(m, off), so_ = __shfl_xor(s, off);
        const float mn = fmaxf(m, mo);
        s = s * __expf(m - mn) + so_ * __expf(mo - mn);
        m = mn;
    }
    const float inv_s = s > 0.f ? 1.f / s : 0.f;

    const int half = lane >> 5;
    const int lsub = lane & 31;
    f16x2 acc00 = {0, 0}, acc01 = {0, 0};
    f16x2 acc10 = {0, 0}, acc11 = {0, 0};
    f16x2 acc20 = {0, 0}, acc21 = {0, 0};

    int ch = 0;
    for (int cb = beg; cb < end; cb += 64, ++ch) {
        const int p = cb + lane;
        float wl = 0.f; int so = 0;
        if (ch == 0) {
            wl = __expf(att0 - m) * inv_s * inv0;
            so = sol0;
        } else if (p < end) {
            so = sord_p[p];
            const int sn = so & 0xFFFF;
            const float4 a0 = pk[2 * sn], a1 = pk[2 * sn + 1];
            const float dx = a0.x - b0.x, dy = a0.y - b0.y, dz = a0.z - b0.z;
            const float a = dx * a0.w + dy * a1.x + dz * a1.y;
            wl = __expf(a - m) * inv_s / (dx * dx + dy * dy + dz * dz + 1.f);
        }
        const int k = so >> 16;
        const __fp16 wh = (__fp16)wl;
        f16x2 w2; w2.x = wh; w2.y = wh;
        const unsigned uw = h2u(w2);
        stash[wid][lane] = make_uint4(k == 0 ? uw : 0u, k == 1 ? uw : 0u,
                                      k == 2 ? uw : 0u, (unsigned)(so & 0xFFFF));
        const int ne = min(64, end - cb);
        const uint4* st = stash[wid];
        for (int t = 0; t < ne; t += 2) {
            const uint4 e = st[t + half];
            const uint2 v = *(const uint2*)((const char*)fh + ((size_t)e.w << 8) + lsub * 8);
            const f16x2 va = u2h(v.x), vb = u2h(v.y);
            acc00 = __builtin_elementwise_fma(va, u2h(e.x), acc00);
            acc01 = __builtin_elementwise_fma(vb, u2h(e.x), acc01);
            acc10 = __builtin_elementwise_fma(va, u2h(e.y), acc10);
            acc11 = __builtin_elementwise_fma(vb, u2h(e.y), acc11);
            acc20 = __builtin_elementwise_fma(va, u2h(e.z), acc20);
            acc21 = __builtin_elementwise_fma(vb, u2h(e.z), acc21);
        }
    }
    acc00 = acc00 + u2h(__shfl_xor((int)h2u(acc00), 32));
    acc01 = acc01 + u2h(__shfl_xor((int)h2u(acc01), 32));
    acc10 = acc10 + u2h(__shfl_xor((int)h2u(acc10), 32));
    acc11 = acc11 + u2h(__shfl_xor((int)h2u(acc11), 32));
    acc20 = acc20 + u2h(__shfl_xor((int)h2u(acc20), 32));
    acc21 = acc21 + u2h(__shfl_xor((int)h2u(acc21), 32));
    if (lane < 32) {
        __fp16* row = agg + (size_t)node * 384 + lsub * 4;
        *(uint2*)(row)       = make_uint2(h2u(acc00), h2u(acc01));
        *(uint2*)(row + 128) = make_uint2(h2u(acc10), h2u(acc11));
        *(uint2*)(row + 256) = make_uint2(h2u(acc20), h2u(acc21));
    }
}

// ============================================================================
// mlp_gemm: y[m,o] = relu(sum_{ki<384} agg[m,ki]*GT[o,ki] + b[o]) + BN stats.
// ONE WAVE per 16 rows x 32 cols; NO LDS, NO barriers; 3125 blocks x 4 waves
// = 12500 independent waves (~5 resident/SIMD at ~90 VGPR). A/B fragments
// loaded directly from global (row-major [.][k] == k-contiguous frag layout).
// 50000 = 3125*16 exactly -> no bounds guards.
// ============================================================================
__global__ __launch_bounds__(256)
void mlp_gemm(const __fp16* __restrict__ agg, const __fp16* __restrict__ GT,
              float* __restrict__ out,
              const float* __restrict__ bias, float* __restrict__ sbuf) {
    const int tid = threadIdx.x;
    const int wave = tid >> 6, lane = tid & 63;
    const int m0 = blockIdx.x * 16;
    const int colbase = wave * 32;
    const int lrow = lane & 15;
    const int kg = lane >> 4;          // 0..3

    // A fragments: full K=384 for 16 rows (12 x f16x8 per lane)
    const __fp16* ap = agg + (size_t)(m0 + lrow) * 384 + kg * 8;
    f16x8 afr[12];
    #pragma unroll
    for (int ks = 0; ks < 12; ++ks) afr[ks] = *(const f16x8*)(ap + ks * 32);

    f32x4 acc0 = (f32x4){0.f, 0.f, 0.f, 0.f};
    f32x4 acc1 = (f32x4){0.f, 0.f, 0.f, 0.f};
    const __fp16* bp0 = GT + (size_t)(colbase + lrow) * 384 + kg * 8;
    const __fp16* bp1 = GT + (size_t)(colbase + 16 + lrow) * 384 + kg * 8;
    #pragma unroll
    for (int ks = 0; ks < 12; ++ks) {
        const f16x8 b0 = *(const f16x8*)(bp0 + ks * 32);
        const f16x8 b1 = *(const f16x8*)(bp1 + ks * 32);
        acc0 = __builtin_amdgcn_mfma_f32_16x16x32_f16(afr[ks], b0, acc0, 0, 0, 0);
        acc1 = __builtin_amdgcn_mfma_f32_16x16x32_f16(afr[ks], b1, acc1, 0, 0, 0);
    }

    // epilogue: bias + ReLU + store + BN stats
    const float bv0 = bias[colbase + lrow];
    const float bv1 = bias[colbase + 16 + lrow];
    float s0 = 0.f, q0 = 0.f, s1 = 0.f, q1 = 0.f;
    #pragma unroll
    for (int rg = 0; rg < 4; ++rg) {
        const int row = m0 + kg * 4 + rg;
        const float v0 = fmaxf(acc0[rg] + bv0, 0.f);
        const float v1 = fmaxf(acc1[rg] + bv1, 0.f);
        out[(size_t)row * FEAT + colbase + lrow]      = v0;
        out[(size_t)row * FEAT + colbase + 16 + lrow] = v1;
        s0 += v0; q0 = fmaf(v0, v0, q0);
        s1 += v1; q1 = fmaf(v1, v1, q1);
    }
    s0 += __shfl_xor(s0, 16); s0 += __shfl_xor(s0, 32);
    q0 += __shfl_xor(q0, 16); q0 += __shfl_xor(q0, 32);
    s1 += __shfl_xor(s1, 16); s1 += __shfl_xor(s1, 32);
    q1 += __shfl_xor(q1, 16); q1 += __shfl_xor(q1, 32);
    if (lane < 16) {
        float* sb = sbuf + (blockIdx.x & (NSHARD - 1)) * 256;
        atomicAdd(sb + colbase + lrow, s0);
        atomicAdd(sb + colbase + 16 + lrow, s1);
        atomicAdd(sb + 128 + colbase + lrow, q0);
        atomicAdd(sb + 128 + colbase + 16 + lrow, q1);
    }
}

// ---- BN normalize (sums the 16 stat shards, derives scale/shift) ----
__global__ void normalize(float* __restrict__ y, const float* __restrict__ sbuf,
                          const float* __restrict__ gamma, const float* __restrict__ beta) {
    __shared__ float sc_s[FEAT], sh_s[FEAT];
    const int t = threadIdx.x;
    if (t < FEAT) {
        float ssum = 0.f, qsum = 0.f;
        #pragma unroll
        for (int sh = 0; sh < NSHARD; ++sh) {
            ssum += sbuf[sh * 256 + t];
            qsum += sbuf[sh * 256 + 128 + t];
        }
        const float mean = ssum / (float)N_NODES;
        const float var  = qsum / (float)N_NODES - mean * mean;
        const float sc   = gamma[t] * rsqrtf(var + BN_EPS);
        sc_s[t] = sc;
        sh_s[t] = beta[t] - mean * sc;
    }
    __syncthreads();
    const int idx = blockIdx.x * blockDim.x + t;
    const int o4 = (idx & 31) * 4;
    float4 v = *(float4*)(y + (size_t)idx * 4);
    const float4 sc = *(const float4*)(sc_s + o4);
    const float4 sh = *(const float4*)(sh_s + o4);
    v.x = fmaf(v.x, sc.x, sh.x);
    v.y = fmaf(v.y, sc.y, sh.y);
    v.z = fmaf(v.z, sc.z, sh.z);
    v.w = fmaf(v.w, sc.w, sh.w);
    *(float4*)(y + (size_t)idx * 4) = v;
}

extern "C" void kernel_launch(void* const* d_in, const int* in_sizes, int n_in,
                              void* d_out, int out_size, void* d_ws, size_t ws_size,
                              hipStream_t stream) {
    const float* feature = (const float*)d_in[0];
    const float* coords  = (const float*)d_in[1];
    const int*   src     = (const int*)d_in[2];
    const int*   dst     = (const int*)d_in[3];
    const int*   order   = (const int*)d_in[4];
    const float* linear  = (const float*)d_in[5];
    const float* attW    = (const float*)d_in[6];
    const float* mlp_w   = (const float*)d_in[7];
    const float* mlp_b   = (const float*)d_in[8];
    const float* gamma   = (const float*)d_in[9];
    const float* beta    = (const float*)d_in[10];
    float* out = (float*)d_out;

    char* p = (char*)d_ws;
    __fp16* fh           = (__fp16*)p;  p += (size_t)N_NODES * FEAT * 2;   // 12.8 MB
    __fp16* agg          = (__fp16*)p;  p += (size_t)N_NODES * 384 * 2;    // 38.4 MB
    __fp16* GT           = (__fp16*)p;  p += (size_t)FEAT * 384 * 2;       // 98 KB
    float4* pk           = (float4*)p;  p += (size_t)N_NODES * 32;         // 1.6 MB
    int*   sord_p        = (int*)p;     p += (size_t)E_EDGES * 4;          // 3.2 MB
    int2*  bbuf          = (int2*)p;    p += (size_t)NBUK * BCAP * 8;      // 8.0 MB
    int*   cnt           = (int*)p;     p += 200064;
    float* sbuf          = (float*)p;   p += NSHARD * 256 * 4;             // 16 KB
    int*   gcur          = (int*)p;     p += 1024;   // memset covers cnt+sbuf+gcur
    int*   rowptr        = (int*)p;     p += 200064;
    int*   cursor        = (int*)p;     p += 200064;
    int*   bsum          = (int*)p;     p += 256;

    hipMemsetAsync(cnt, 0, 200064 + NSHARD * 256 * 4 + 1024, stream);

    const int AB = (E_EDGES + 2047) / 2048;      // 391

    g_cast<<<NWB_BLKS + FEAT, 256, 0, stream>>>(feature, coords, attW,
                                                mlp_w, linear, fh, pk, GT);

    bucketA<<<AB, 256, 0, stream>>>(src, dst, order, cnt, gcur, bbuf);
    scan1<<<NB1, 256, 0, stream>>>(cnt, rowptr, bsum);
    scan3<<<(N_NODES + 255) / 256, 256, 0, stream>>>(rowptr, cursor, bsum);
    bucketB<<<NBUK * 8, 256, 0, stream>>>(gcur, bbuf, cursor, sord_p);

    segagg<<<NWB_BLKS, 256, 0, stream>>>(pk, sord_p, rowptr, fh, agg);

    mlp_gemm<<<N_NODES / 16, 256, 0, stream>>>(agg, GT, out, mlp_b, sbuf);
    normalize<<<(N_NODES * 32) / 256, 256, 0, stream>>>(out, sbuf, gamma, beta);
}

// Round 15
// 191.924 us; speedup vs baseline: 1.1672x; 1.1672x over previous
//
#include <hip/hip_runtime.h>

#define N_NODES 50000
#define E_EDGES 800000
#define FEAT    128
#define KORD    3
#define BN_EPS  1e-5f
#define NB1     49          // ceil(50000/1024) scan blocks
#define NBUK    49          // coarse buckets (dst >> 10)
#define BCAP    20480       // bucket capacity
#define NSHARD  16          // BN-stats atomic shards

typedef __fp16 f16x2 __attribute__((ext_vector_type(2)));
typedef __fp16 f16x8 __attribute__((ext_vector_type(8)));
typedef __attribute__((ext_vector_type(4))) float f32x4;

__device__ __forceinline__ unsigned h2u(f16x2 h) { union { f16x2 h; unsigned u; } c; c.h = h; return c.u; }
__device__ __forceinline__ f16x2 u2h(unsigned u) { union { unsigned u; f16x2 h; } c; c.u = u; return c.h; }

// async global->LDS, 16B per lane (lane lands at ldsbase + lane*16)
__device__ __forceinline__ void gload16(const void* g, void* l) {
    __builtin_amdgcn_global_load_lds(
        (const __attribute__((address_space(1))) unsigned int*)g,
        (__attribute__((address_space(3))) unsigned int*)l, 16, 0, 0);
}

// ---- fold the two linear layers: GT[o][k*128+i] = sum_j L[k][i][j] * W[o][j]
__global__ void gprep(const float* __restrict__ W, const float* __restrict__ L,
                      __fp16* __restrict__ GT) {
    __shared__ float wrow[FEAT];
    const int o = blockIdx.x;      // 128
    const int i = threadIdx.x;     // 128
    wrow[i] = W[o * FEAT + i];
    __syncthreads();
    #pragma unroll
    for (int k = 0; k < KORD; ++k) {
        const float* lp = L + ((size_t)k * FEAT + i) * FEAT;
        float acc = 0.f;
        #pragma unroll 8
        for (int j = 0; j < FEAT; ++j) acc = fmaf(lp[j], wrow[j], acc);
        GT[(size_t)o * 384 + k * FEAT + i] = (__fp16)acc;
    }
}

// ---- per node: feature->f16, and pack {coords, g=attW@f} into 2 float4 ----
__global__ void g_cast(const float* __restrict__ feat,
                       const float* __restrict__ coords,
                       const float* __restrict__ attW,
                       __fp16* __restrict__ fh,
                       float4* __restrict__ pk) {
    const int node = (blockIdx.x * blockDim.x + threadIdx.x) >> 6;
    const int lane = threadIdx.x & 63;
    if (node >= N_NODES) return;
    const float2 f = *(const float2*)(feat + (size_t)node * FEAT + lane * 2);
    *(f16x2*)(fh + (size_t)node * FEAT + lane * 2) = __builtin_amdgcn_cvt_pkrtz(f.x, f.y);
    float gg[3];
    #pragma unroll
    for (int j = 0; j < 3; ++j) {
        float p = f.x * attW[j * FEAT + lane * 2] + f.y * attW[j * FEAT + lane * 2 + 1];
        #pragma unroll
        for (int off = 32; off; off >>= 1) p += __shfl_xor(p, off);
        gg[j] = p;
    }
    if (lane == 0) {
        const float c0 = coords[node * 3 + 0], c1 = coords[node * 3 + 1], c2 = coords[node * 3 + 2];
        pk[2 * node]     = make_float4(c0, c1, c2, gg[0]);
        pk[2 * node + 1] = make_float4(gg[1], gg[2], 0.f, 0.f);
    }
}

// ============ CSR build ============
__global__ __launch_bounds__(256)
void bucketA(const int* __restrict__ src, const int* __restrict__ dst,
             const int* __restrict__ order,
             int* __restrict__ cnt, int* __restrict__ gcur, int2* __restrict__ bbuf) {
    __shared__ int lcnt[NBUK];
    __shared__ int lbase[NBUK];
    const int tid = threadIdx.x;
    if (tid < NBUK) lcnt[tid] = 0;
    __syncthreads();
    const int e0 = blockIdx.x * 2048;
    int b[8], r[8], so[8], dd[8];
    #pragma unroll
    for (int i = 0; i < 8; ++i) {
        const int e = e0 + i * 256 + tid;
        if (e < E_EDGES) {
            dd[i] = dst[e];
            so[i] = (order[e] << 16) | src[e];
            b[i] = dd[i] >> 10;
            r[i] = atomicAdd(&lcnt[b[i]], 1);
            atomicAdd(cnt + dd[i], 1);
        } else b[i] = -1;
    }
    __syncthreads();
    if (tid < NBUK) lbase[tid] = atomicAdd(&gcur[tid], lcnt[tid]);
    __syncthreads();
    #pragma unroll
    for (int i = 0; i < 8; ++i)
        if (b[i] >= 0)
            bbuf[(size_t)b[i] * BCAP + lbase[b[i]] + r[i]] = make_int2(so[i], dd[i]);
}

__global__ __launch_bounds__(256)
void scan1(const int* __restrict__ cnt, int* __restrict__ rowptr, int* __restrict__ bsum) {
    __shared__ int lds[256];
    const int b = blockIdx.x, t = threadIdx.x;
    const int base = b * 1024 + t * 4;
    int v[4];
    #pragma unroll
    for (int i = 0; i < 4; ++i) v[i] = (base + i < N_NODES) ? cnt[base + i] : 0;
    lds[t] = v[0] + v[1] + v[2] + v[3];
    __syncthreads();
    for (int off = 1; off < 256; off <<= 1) {
        const int u = (t >= off) ? lds[t - off] : 0;
        __syncthreads();
        lds[t] += u;
        __syncthreads();
    }
    int excl = t ? lds[t - 1] : 0;
    if (t == 255) bsum[b] = lds[255];
    #pragma unroll
    for (int i = 0; i < 4; ++i) {
        if (base + i < N_NODES) rowptr[base + i] = excl;
        excl += v[i];
    }
}

__global__ void scan2(const int* __restrict__ bsum, int* __restrict__ boff,
                      int* __restrict__ rowptr) {
    const int lane = threadIdx.x;   // 64
    const int v = (lane < NB1) ? bsum[lane] : 0;
    int incl = v;
    #pragma unroll
    for (int off = 1; off < 64; off <<= 1) {
        const int u = __shfl_up(incl, off);
        if (lane >= off) incl += u;
    }
    if (lane < NB1) boff[lane] = incl - v;
    if (lane == 0) rowptr[N_NODES] = E_EDGES;
}

__global__ void scan3(int* __restrict__ rowptr, int* __restrict__ cursor,
                      const int* __restrict__ boff) {
    const int i = blockIdx.x * blockDim.x + threadIdx.x;
    if (i >= N_NODES) return;
    const int v = rowptr[i] + boff[i >> 10];
    rowptr[i] = v;
    cursor[i] = v;
}

__global__ void bucketB(const int* __restrict__ gcur, const int2* __restrict__ bbuf,
                        int* __restrict__ cursor, int* __restrict__ sord_p) {
    const int b = blockIdx.x >> 3;
    const int seg = blockIdx.x & 7;
    const int n = gcur[b];
    const int lo = (int)((long)n * seg / 8), hi = (int)((long)n * (seg + 1) / 8);
    for (int i = lo + (int)threadIdx.x; i < hi; i += 256) {
        const int2 ent = bbuf[(size_t)b * BCAP + i];
        const int pos = atomicAdd(cursor + ent.y, 1);
        sord_p[pos] = ent.x;
    }
}

// ---- fused edge-att + segment softmax + per-order gather-aggregate ----
__global__ void segagg(const float4* __restrict__ pk,
                       const int* __restrict__ sord_p,
                       const int* __restrict__ rowptr,
                       const __fp16* __restrict__ fh,
                       __fp16* __restrict__ agg) {
    __shared__ uint4 stash[4][64];
    const int node = (blockIdx.x * blockDim.x + threadIdx.x) >> 6;
    const int lane = threadIdx.x & 63;
    const int wid  = threadIdx.x >> 6;
    if (node >= N_NODES) return;
    const int beg = rowptr[node], end = rowptr[node + 1];
    const float4 b0 = pk[2 * node];

    float att0 = -1e30f, inv0 = 0.f; int sol0 = 0;
    float m = -1e30f, s = 0.f;
    int nch = 0;
    for (int cb = beg; cb < end; cb += 64, ++nch) {
        const int p = cb + lane;
        float a = -1e30f, iv = 0.f; int so = 0;
        if (p < end) {
            so = sord_p[p];
            const int sn = so & 0xFFFF;
            const float4 a0 = pk[2 * sn], a1 = pk[2 * sn + 1];
            const float dx = a0.x - b0.x, dy = a0.y - b0.y, dz = a0.z - b0.z;
            a = dx * a0.w + dy * a1.x + dz * a1.y;
            iv = 1.f / (dx * dx + dy * dy + dz * dz + 1.f);
        }
        if (nch == 0) { att0 = a; inv0 = iv; sol0 = so; }
        const float mn = fmaxf(m, a);
        s = s * __expf(m - mn) + ((p < end) ? __expf(a - mn) : 0.f);
        m = mn;
    }
    #pragma unroll
    for (int off = 32; off; off >>= 1) {
        const float mo = __shfl_xor(m, off), so_ = __shfl_xor(s, off);
        const float mn = fmaxf(m, mo);
        s = s * __expf(m - mn) + so_ * __expf(mo - mn);
        m = mn;
    }
    const float inv_s = s > 0.f ? 1.f / s : 0.f;

    const int half = lane >> 5;
    const int lsub = lane & 31;
    f16x2 acc00 = {0, 0}, acc01 = {0, 0};
    f16x2 acc10 = {0, 0}, acc11 = {0, 0};
    f16x2 acc20 = {0, 0}, acc21 = {0, 0};

    int ch = 0;
    for (int cb = beg; cb < end; cb += 64, ++ch) {
        const int p = cb + lane;
        float wl = 0.f; int so = 0;
        if (ch == 0) {
            wl = __expf(att0 - m) * inv_s * inv0;
            so = sol0;
        } else if (p < end) {
            so = sord_p[p];
            const int sn = so & 0xFFFF;
            const float4 a0 = pk[2 * sn], a1 = pk[2 * sn + 1];
            const float dx = a0.x - b0.x, dy = a0.y - b0.y, dz = a0.z - b0.z;
            const float a = dx * a0.w + dy * a1.x + dz * a1.y;
            wl = __expf(a - m) * inv_s / (dx * dx + dy * dy + dz * dz + 1.f);
        }
        const int k = so >> 16;
        const __fp16 wh = (__fp16)wl;
        f16x2 w2; w2.x = wh; w2.y = wh;
        const unsigned uw = h2u(w2);
        stash[wid][lane] = make_uint4(k == 0 ? uw : 0u, k == 1 ? uw : 0u,
                                      k == 2 ? uw : 0u, (unsigned)(so & 0xFFFF));
        const int ne = min(64, end - cb);
        const uint4* st = stash[wid];
        for (int t = 0; t < ne; t += 2) {
            const uint4 e = st[t + half];
            const uint2 v = *(const uint2*)((const char*)fh + ((size_t)e.w << 8) + lsub * 8);
            const f16x2 va = u2h(v.x), vb = u2h(v.y);
            acc00 = __builtin_elementwise_fma(va, u2h(e.x), acc00);
            acc01 = __builtin_elementwise_fma(vb, u2h(e.x), acc01);
            acc10 = __builtin_elementwise_fma(va, u2h(e.y), acc10);
            acc11 = __builtin_elementwise_fma(vb, u2h(e.y), acc11);
            acc20 = __builtin_elementwise_fma(va, u2h(e.z), acc20);
            acc21 = __builtin_elementwise_fma(vb, u2h(e.z), acc21);
        }
    }
    acc00 = acc00 + u2h(__shfl_xor((int)h2u(acc00), 32));
    acc01 = acc01 + u2h(__shfl_xor((int)h2u(acc01), 32));
    acc10 = acc10 + u2h(__shfl_xor((int)h2u(acc10), 32));
    acc11 = acc11 + u2h(__shfl_xor((int)h2u(acc11), 32));
    acc20 = acc20 + u2h(__shfl_xor((int)h2u(acc20), 32));
    acc21 = acc21 + u2h(__shfl_xor((int)h2u(acc21), 32));
    if (lane < 32) {
        __fp16* row = agg + (size_t)node * 384 + lsub * 4;
        *(uint2*)(row)       = make_uint2(h2u(acc00), h2u(acc01));
        *(uint2*)(row + 128) = make_uint2(h2u(acc10), h2u(acc11));
        *(uint2*)(row + 256) = make_uint2(h2u(acc20), h2u(acc21));
    }
}

// ============================================================================
// mlp_gemm: y[m,o] = relu(sum_{ki<384} agg[m,ki]*GT[o,ki] + b[o]) + BN stats.
// 64-row M-tile, K-step 64, DOUBLE-BUFFERED async staging via
// global_load_lds(16B) with PRE-SWIZZLED global source (linear LDS dest,
// chunk ^= row&7 involution on 16B chunks); T3 2-phase: STAGE(next) ||
// ds_read+MFMA(cur); one barrier per k-step. 48KB LDS -> 3 blocks/CU.
// ============================================================================
__global__ __launch_bounds__(256)
void mlp_gemm(const __fp16* __restrict__ agg, const __fp16* __restrict__ GT,
              float* __restrict__ out, int M,
              const float* __restrict__ bias, float* __restrict__ sbuf) {
    __shared__ char smem[49152];     // buf b: A at b*24576 (8KB), B at +8192 (16KB)
    const int m0 = blockIdx.x * 64;
    const int tid = threadIdx.x;
    const int wave = tid >> 6, lane = tid & 63;
    const int wm0 = wave * 16;
    const int lrow = lane & 15;
    const int kg = lane >> 4;          // 0..3
    const int srow = lane >> 3;        // 0..7 (staging row within 8-row group)
    const int schunk = lane & 7;       // 0..7 (16B chunk within 128B row)

    // ---- stage k-chunk kc (64 f16) into buffer buf (async) ----
    auto STAGE = [&](int buf, int kc) {
        char* base = smem + buf * 24576;
        #pragma unroll
        for (int j = 0; j < 2; ++j) {                 // A: 2 x 8 rows per wave
            const int rl = wave * 16 + j * 8 + srow;  // 0..63
            const int rg = min(m0 + rl, M - 1);
            gload16(agg + (size_t)rg * 384 + kc * 64 + ((schunk ^ (rl & 7)) << 3),
                    base + (wave * 16 + j * 8) * 128);
        }
        #pragma unroll
        for (int j = 0; j < 4; ++j) {                 // B: 4 x 8 rows per wave
            const int rl = wave * 32 + j * 8 + srow;  // 0..127
            gload16(GT + (size_t)rl * 384 + kc * 64 + ((schunk ^ (rl & 7)) << 3),
                    base + 8192 + (wave * 32 + j * 8) * 128);
        }
    };

    f32x4 acc[8];
    #pragma unroll
    for (int b = 0; b < 8; ++b) acc[b] = (f32x4){0.f, 0.f, 0.f, 0.f};

    STAGE(0, 0);
    __syncthreads();                                  // drain prologue stage

    for (int kc = 0; kc < 6; ++kc) {
        const int buf = kc & 1;
        if (kc < 5) STAGE(buf ^ 1, kc + 1);           // async, in flight during MFMA
        const char* Ab = smem + buf * 24576;
        const char* Bb = Ab + 8192;
        f16x8 afr[2];
        #pragma unroll
        for (int ks = 0; ks < 2; ++ks) {
            const int row = wm0 + lrow;
            afr[ks] = *(const f16x8*)(Ab + row * 128 + (((ks * 4 + kg) ^ (row & 7)) << 4));
        }
        #pragma unroll
        for (int nf = 0; nf < 8; ++nf) {
            #pragma unroll
            for (int ks = 0; ks < 2; ++ks) {
                const int row = nf * 16 + lrow;
                f16x8 bfr = *(const f16x8*)(Bb + row * 128 + (((ks * 4 + kg) ^ (row & 7)) << 4));
                acc[nf] = __builtin_amdgcn_mfma_f32_16x16x32_f16(afr[ks], bfr, acc[nf], 0, 0, 0);
            }
        }
        __syncthreads();   // all waves done reading buf; next stage drained
    }

    // ---- epilogue: bias + ReLU + store f32 + BN column stats (sharded) ----
    float s[8], s2[8], bv[8];
    #pragma unroll
    for (int nf = 0; nf < 8; ++nf) { s[nf] = 0.f; s2[nf] = 0.f; bv[nf] = bias[nf * 16 + lrow]; }
    #pragma unroll
    for (int nf = 0; nf < 8; ++nf)
        #pragma unroll
        for (int rg = 0; rg < 4; ++rg) {
            const int row = m0 + wm0 + kg * 4 + rg;
            if (row < M) {
                const float v = fmaxf(acc[nf][rg] + bv[nf], 0.f);
                out[(size_t)row * FEAT + nf * 16 + lrow] = v;
                s[nf] += v;
                s2[nf] = fmaf(v, v, s2[nf]);
            }
        }
    #pragma unroll
    for (int nf = 0; nf < 8; ++nf) {
        s[nf]  += __shfl_xor(s[nf], 16);  s[nf]  += __shfl_xor(s[nf], 32);
        s2[nf] += __shfl_xor(s2[nf], 16); s2[nf] += __shfl_xor(s2[nf], 32);
    }
    __syncthreads();
    float* red = (float*)smem;                // [4][256]
    if (lane < 16) {
        #pragma unroll
        for (int nf = 0; nf < 8; ++nf) {
            red[wave * 256 + nf * 16 + lane]       = s[nf];
            red[wave * 256 + 128 + nf * 16 + lane] = s2[nf];
        }
    }
    __syncthreads();
    if (tid < 128) {
        const float ss = red[tid] + red[256 + tid] + red[512 + tid] + red[768 + tid];
        const float qq = red[128 + tid] + red[384 + tid] + red[640 + tid] + red[896 + tid];
        float* sb = sbuf + (blockIdx.x & (NSHARD - 1)) * 256;
        atomicAdd(sb + tid, ss);
        atomicAdd(sb + FEAT + tid, qq);
    }
}

// ---- BN normalize (sums the 16 stat shards, derives scale/shift) ----
__global__ void normalize(float* __restrict__ y, const float* __restrict__ sbuf,
                          const float* __restrict__ gamma, const float* __restrict__ beta) {
    __shared__ float sc_s[FEAT], sh_s[FEAT];
    const int t = threadIdx.x;
    if (t < FEAT) {
        float ssum = 0.f, qsum = 0.f;
        #pragma unroll
        for (int sh = 0; sh < NSHARD; ++sh) {
            ssum += sbuf[sh * 256 + t];
            qsum += sbuf[sh * 256 + 128 + t];
        }
        const float mean = ssum / (float)N_NODES;
        const float var  = qsum / (float)N_NODES - mean * mean;
        const float sc   = gamma[t] * rsqrtf(var + BN_EPS);
        sc_s[t] = sc;
        sh_s[t] = beta[t] - mean * sc;
    }
    __syncthreads();
    const int idx = blockIdx.x * blockDim.x + t;
    const int o4 = (idx & 31) * 4;
    float4 v = *(float4*)(y + (size_t)idx * 4);
    const float4 sc = *(const float4*)(sc_s + o4);
    const float4 sh = *(const float4*)(sh_s + o4);
    v.x = fmaf(v.x, sc.x, sh.x);
    v.y = fmaf(v.y, sc.y, sh.y);
    v.z = fmaf(v.z, sc.z, sh.z);
    v.w = fmaf(v.w, sc.w, sh.w);
    *(float4*)(y + (size_t)idx * 4) = v;
}

extern "C" void kernel_launch(void* const* d_in, const int* in_sizes, int n_in,
                              void* d_out, int out_size, void* d_ws, size_t ws_size,
                              hipStream_t stream) {
    const float* feature = (const float*)d_in[0];
    const float* coords  = (const float*)d_in[1];
    const int*   src     = (const int*)d_in[2];
    const int*   dst     = (const int*)d_in[3];
    const int*   order   = (const int*)d_in[4];
    const float* linear  = (const float*)d_in[5];
    const float* attW    = (const float*)d_in[6];
    const float* mlp_w   = (const float*)d_in[7];
    const float* mlp_b   = (const float*)d_in[8];
    const float* gamma   = (const float*)d_in[9];
    const float* beta    = (const float*)d_in[10];
    float* out = (float*)d_out;

    char* p = (char*)d_ws;
    __fp16* fh           = (__fp16*)p;  p += (size_t)N_NODES * FEAT * 2;   // 12.8 MB
    __fp16* agg          = (__fp16*)p;  p += (size_t)N_NODES * 384 * 2;    // 38.4 MB
    __fp16* GT           = (__fp16*)p;  p += (size_t)FEAT * 384 * 2;       // 98 KB
    float4* pk           = (float4*)p;  p += (size_t)N_NODES * 32;         // 1.6 MB
    int*   sord_p        = (int*)p;     p += (size_t)E_EDGES * 4;          // 3.2 MB
    int2*  bbuf          = (int2*)p;    p += (size_t)NBUK * BCAP * 8;      // 8.0 MB
    int*   cnt           = (int*)p;     p += 200064;
    float* sbuf          = (float*)p;   p += NSHARD * 256 * 4;             // 16 KB
    int*   gcur          = (int*)p;     p += 1024;   // memset covers cnt+sbuf+gcur
    int*   rowptr        = (int*)p;     p += 200064;
    int*   cursor        = (int*)p;     p += 200064;
    int*   bsum          = (int*)p;     p += 256;
    int*   boff          = (int*)p;     p += 256;

    hipMemsetAsync(cnt, 0, 200064 + NSHARD * 256 * 4 + 1024, stream);

    const int NWB = (N_NODES * 64) / 256;         // 12500
    const int MB  = (N_NODES + 63) / 64;          // 782
    const int AB  = (E_EDGES + 2047) / 2048;      // 391

    gprep<<<FEAT, FEAT, 0, stream>>>(mlp_w, linear, GT);
    g_cast<<<NWB, 256, 0, stream>>>(feature, coords, attW, fh, pk);

    bucketA<<<AB, 256, 0, stream>>>(src, dst, order, cnt, gcur, bbuf);
    scan1<<<NB1, 256, 0, stream>>>(cnt, rowptr, bsum);
    scan2<<<1, 64, 0, stream>>>(bsum, boff, rowptr);
    scan3<<<(N_NODES + 255) / 256, 256, 0, stream>>>(rowptr, cursor, boff);
    bucketB<<<NBUK * 8, 256, 0, stream>>>(gcur, bbuf, cursor, sord_p);

    segagg<<<NWB, 256, 0, stream>>>(pk, sord_p, rowptr, fh, agg);

    mlp_gemm<<<MB, 256, 0, stream>>>(agg, GT, out, N_NODES, mlp_b, sbuf);
    normalize<<<(N_NODES * 32) / 256, 256, 0, stream>>>(out, sbuf, gamma, beta);
}

// Round 16
// 186.157 us; speedup vs baseline: 1.2034x; 1.0310x over previous
//
#include <hip/hip_runtime.h>

#define N_NODES 50000
#define E_EDGES 800000
#define FEAT    128
#define KORD    3
#define BN_EPS  1e-5f
#define NB1     49          // ceil(50000/1024) scan blocks
#define NBUK    49          // coarse buckets (dst >> 10)
#define BCAP    20480       // bucket capacity
#define NSHARD  16          // BN-stats atomic shards

typedef __fp16 f16x2 __attribute__((ext_vector_type(2)));
typedef __fp16 f16x8 __attribute__((ext_vector_type(8)));
typedef __attribute__((ext_vector_type(4))) float f32x4;

__device__ __forceinline__ unsigned h2u(f16x2 h) { union { f16x2 h; unsigned u; } c; c.h = h; return c.u; }
__device__ __forceinline__ f16x2 u2h(unsigned u) { union { unsigned u; f16x2 h; } c; c.u = u; return c.h; }

// async global->LDS, 16B per lane (lane lands at ldsbase + lane*16)
__device__ __forceinline__ void gload16(const void* g, void* l) {
    __builtin_amdgcn_global_load_lds(
        (const __attribute__((address_space(1))) unsigned int*)g,
        (__attribute__((address_space(3))) unsigned int*)l, 16, 0, 0);
}

// ---- fold the two linear layers: GT[o][k*128+i] = sum_j L[k][i][j] * W[o][j]
__global__ void gprep(const float* __restrict__ W, const float* __restrict__ L,
                      __fp16* __restrict__ GT) {
    __shared__ float wrow[FEAT];
    const int o = blockIdx.x;      // 128
    const int i = threadIdx.x;     // 128
    wrow[i] = W[o * FEAT + i];
    __syncthreads();
    #pragma unroll
    for (int k = 0; k < KORD; ++k) {
        const float* lp = L + ((size_t)k * FEAT + i) * FEAT;
        float acc = 0.f;
        #pragma unroll 8
        for (int j = 0; j < FEAT; ++j) acc = fmaf(lp[j], wrow[j], acc);
        GT[(size_t)o * 384 + k * FEAT + i] = (__fp16)acc;
    }
}

// ---- per node: feature->f16, and pack {coords, g=attW@f} into 2 float4 ----
__global__ void g_cast(const float* __restrict__ feat,
                       const float* __restrict__ coords,
                       const float* __restrict__ attW,
                       __fp16* __restrict__ fh,
                       float4* __restrict__ pk) {
    const int node = (blockIdx.x * blockDim.x + threadIdx.x) >> 6;
    const int lane = threadIdx.x & 63;
    if (node >= N_NODES) return;
    const float2 f = *(const float2*)(feat + (size_t)node * FEAT + lane * 2);
    *(f16x2*)(fh + (size_t)node * FEAT + lane * 2) = __builtin_amdgcn_cvt_pkrtz(f.x, f.y);
    float gg[3];
    #pragma unroll
    for (int j = 0; j < 3; ++j) {
        float p = f.x * attW[j * FEAT + lane * 2] + f.y * attW[j * FEAT + lane * 2 + 1];
        #pragma unroll
        for (int off = 32; off; off >>= 1) p += __shfl_xor(p, off);
        gg[j] = p;
    }
    if (lane == 0) {
        const float c0 = coords[node * 3 + 0], c1 = coords[node * 3 + 1], c2 = coords[node * 3 + 2];
        pk[2 * node]     = make_float4(c0, c1, c2, gg[0]);
        pk[2 * node + 1] = make_float4(gg[1], gg[2], 0.f, 0.f);
    }
}

// ============ CSR build ============
__global__ __launch_bounds__(256)
void bucketA(const int* __restrict__ src, const int* __restrict__ dst,
             const int* __restrict__ order,
             int* __restrict__ cnt, int* __restrict__ gcur, int2* __restrict__ bbuf) {
    __shared__ int lcnt[NBUK];
    __shared__ int lbase[NBUK];
    const int tid = threadIdx.x;
    if (tid < NBUK) lcnt[tid] = 0;
    __syncthreads();
    const int e0 = blockIdx.x * 2048;
    int b[8], r[8], so[8], dd[8];
    #pragma unroll
    for (int i = 0; i < 8; ++i) {
        const int e = e0 + i * 256 + tid;
        if (e < E_EDGES) {
            dd[i] = dst[e];
            so[i] = (order[e] << 16) | src[e];
            b[i] = dd[i] >> 10;
            r[i] = atomicAdd(&lcnt[b[i]], 1);
            atomicAdd(cnt + dd[i], 1);
        } else b[i] = -1;
    }
    __syncthreads();
    if (tid < NBUK) lbase[tid] = atomicAdd(&gcur[tid], lcnt[tid]);
    __syncthreads();
    #pragma unroll
    for (int i = 0; i < 8; ++i)
        if (b[i] >= 0)
            bbuf[(size_t)b[i] * BCAP + lbase[b[i]] + r[i]] = make_int2(so[i], dd[i]);
}

__global__ __launch_bounds__(256)
void scan1(const int* __restrict__ cnt, int* __restrict__ rowptr, int* __restrict__ bsum) {
    __shared__ int lds[256];
    const int b = blockIdx.x, t = threadIdx.x;
    const int base = b * 1024 + t * 4;
    int v[4];
    #pragma unroll
    for (int i = 0; i < 4; ++i) v[i] = (base + i < N_NODES) ? cnt[base + i] : 0;
    lds[t] = v[0] + v[1] + v[2] + v[3];
    __syncthreads();
    for (int off = 1; off < 256; off <<= 1) {
        const int u = (t >= off) ? lds[t - off] : 0;
        __syncthreads();
        lds[t] += u;
        __syncthreads();
    }
    int excl = t ? lds[t - 1] : 0;
    if (t == 255) bsum[b] = lds[255];
    #pragma unroll
    for (int i = 0; i < 4; ++i) {
        if (base + i < N_NODES) rowptr[base + i] = excl;
        excl += v[i];
    }
}

__global__ void scan2(const int* __restrict__ bsum, int* __restrict__ boff,
                      int* __restrict__ rowptr) {
    const int lane = threadIdx.x;   // 64
    const int v = (lane < NB1) ? bsum[lane] : 0;
    int incl = v;
    #pragma unroll
    for (int off = 1; off < 64; off <<= 1) {
        const int u = __shfl_up(incl, off);
        if (lane >= off) incl += u;
    }
    if (lane < NB1) boff[lane] = incl - v;
    if (lane == 0) rowptr[N_NODES] = E_EDGES;
}

__global__ void scan3(int* __restrict__ rowptr, int* __restrict__ cursor,
                      const int* __restrict__ boff) {
    const int i = blockIdx.x * blockDim.x + threadIdx.x;
    if (i >= N_NODES) return;
    const int v = rowptr[i] + boff[i >> 10];
    rowptr[i] = v;
    cursor[i] = v;
}

__global__ void bucketB(const int* __restrict__ gcur, const int2* __restrict__ bbuf,
                        int* __restrict__ cursor, int* __restrict__ sord_p) {
    const int b = blockIdx.x >> 3;
    const int seg = blockIdx.x & 7;
    const int n = gcur[b];
    const int lo = (int)((long)n * seg / 8), hi = (int)((long)n * (seg + 1) / 8);
    for (int i = lo + (int)threadIdx.x; i < hi; i += 256) {
        const int2 ent = bbuf[(size_t)b * BCAP + i];
        const int pos = atomicAdd(cursor + ent.y, 1);
        sord_p[pos] = ent.x;
    }
}

// ---- fused edge-att + segment softmax + per-order gather-aggregate ----
// Phase 2: 4 edges x 16-lane groups x 8 feats (16B/lane) -> 4 row-gathers
// in flight per wave, half the dependent-chain iterations of the 2-edge form.
__global__ void segagg(const float4* __restrict__ pk,
                       const int* __restrict__ sord_p,
                       const int* __restrict__ rowptr,
                       const __fp16* __restrict__ fh,
                       __fp16* __restrict__ agg) {
    __shared__ uint4 stash[4][72];          // 64 live + 8 zero-weight pad
    const int node = (blockIdx.x * blockDim.x + threadIdx.x) >> 6;
    const int lane = threadIdx.x & 63;
    const int wid  = threadIdx.x >> 6;
    if (node >= N_NODES) return;
    const int beg = rowptr[node], end = rowptr[node + 1];
    const float4 b0 = pk[2 * node];

    if (lane < 8) stash[wid][64 + lane] = make_uint4(0u, 0u, 0u, 0u);

    // phase 1: online (m,s); cache chunk-0 (deg<=64 covers ~all nodes)
    float att0 = -1e30f, inv0 = 0.f; int sol0 = 0;
    float m = -1e30f, s = 0.f;
    int nch = 0;
    for (int cb = beg; cb < end; cb += 64, ++nch) {
        const int p = cb + lane;
        float a = -1e30f, iv = 0.f; int so = 0;
        if (p < end) {
            so = sord_p[p];
            const int sn = so & 0xFFFF;
            const float4 a0 = pk[2 * sn], a1 = pk[2 * sn + 1];
            const float dx = a0.x - b0.x, dy = a0.y - b0.y, dz = a0.z - b0.z;
            a = dx * a0.w + dy * a1.x + dz * a1.y;
            iv = 1.f / (dx * dx + dy * dy + dz * dz + 1.f);
        }
        if (nch == 0) { att0 = a; inv0 = iv; sol0 = so; }
        const float mn = fmaxf(m, a);
        s = s * __expf(m - mn) + ((p < end) ? __expf(a - mn) : 0.f);
        m = mn;
    }
    #pragma unroll
    for (int off = 32; off; off >>= 1) {
        const float mo = __shfl_xor(m, off), so_ = __shfl_xor(s, off);
        const float mn = fmaxf(m, mo);
        s = s * __expf(m - mn) + so_ * __expf(mo - mn);
        m = mn;
    }
    const float inv_s = s > 0.f ? 1.f / s : 0.f;

    // phase 2: 4-edge groups
    const int grp = lane >> 4;          // 0..3: edge slot within quad
    const int fl  = lane & 15;          // feature slice fl*8 .. fl*8+7
    f16x2 ac[3][4];
    #pragma unroll
    for (int o = 0; o < 3; ++o)
        #pragma unroll
        for (int q = 0; q < 4; ++q) ac[o][q] = (f16x2){0, 0};

    int ch = 0;
    for (int cb = beg; cb < end; cb += 64, ++ch) {
        const int p = cb + lane;
        float wl = 0.f; int so = 0;
        if (ch == 0) {
            wl = __expf(att0 - m) * inv_s * inv0;   // dead lanes: 0
            so = sol0;
        } else if (p < end) {
            so = sord_p[p];
            const int sn = so & 0xFFFF;
            const float4 a0 = pk[2 * sn], a1 = pk[2 * sn + 1];
            const float dx = a0.x - b0.x, dy = a0.y - b0.y, dz = a0.z - b0.z;
            const float a = dx * a0.w + dy * a1.x + dz * a1.y;
            wl = __expf(a - m) * inv_s / (dx * dx + dy * dy + dz * dz + 1.f);
        }
        const int k = so >> 16;
        const __fp16 wh = (__fp16)wl;
        f16x2 w2; w2.x = wh; w2.y = wh;
        const unsigned uw = h2u(w2);
        stash[wid][lane] = make_uint4(k == 0 ? uw : 0u, k == 1 ? uw : 0u,
                                      k == 2 ? uw : 0u, (unsigned)(so & 0xFFFF));
        const int ne = min(64, end - cb);
        const uint4* st = stash[wid];
        for (int t = 0; t < ne; t += 4) {
            const uint4 e = st[t + grp];   // pad entries are zero-weight
            const uint4 v = *(const uint4*)(fh + ((size_t)e.w << 7) + fl * 8);
            const f16x2 w0 = u2h(e.x), w1 = u2h(e.y), w2v = u2h(e.z);
            const f16x2 va = u2h(v.x), vb = u2h(v.y), vc = u2h(v.z), vd = u2h(v.w);
            ac[0][0] = __builtin_elementwise_fma(va, w0, ac[0][0]);
            ac[0][1] = __builtin_elementwise_fma(vb, w0, ac[0][1]);
            ac[0][2] = __builtin_elementwise_fma(vc, w0, ac[0][2]);
            ac[0][3] = __builtin_elementwise_fma(vd, w0, ac[0][3]);
            ac[1][0] = __builtin_elementwise_fma(va, w1, ac[1][0]);
            ac[1][1] = __builtin_elementwise_fma(vb, w1, ac[1][1]);
            ac[1][2] = __builtin_elementwise_fma(vc, w1, ac[1][2]);
            ac[1][3] = __builtin_elementwise_fma(vd, w1, ac[1][3]);
            ac[2][0] = __builtin_elementwise_fma(va, w2v, ac[2][0]);
            ac[2][1] = __builtin_elementwise_fma(vb, w2v, ac[2][1]);
            ac[2][2] = __builtin_elementwise_fma(vc, w2v, ac[2][2]);
            ac[2][3] = __builtin_elementwise_fma(vd, w2v, ac[2][3]);
        }
    }
    // reduce across the 4 edge-groups (lanes fl, fl+16, fl+32, fl+48)
    #pragma unroll
    for (int o = 0; o < 3; ++o)
        #pragma unroll
        for (int q = 0; q < 4; ++q) {
            ac[o][q] = ac[o][q] + u2h(__shfl_xor((int)h2u(ac[o][q]), 16));
            ac[o][q] = ac[o][q] + u2h(__shfl_xor((int)h2u(ac[o][q]), 32));
        }
    if (lane < 16) {
        __fp16* row = agg + (size_t)node * 384 + fl * 8;
        *(uint4*)(row)       = make_uint4(h2u(ac[0][0]), h2u(ac[0][1]), h2u(ac[0][2]), h2u(ac[0][3]));
        *(uint4*)(row + 128) = make_uint4(h2u(ac[1][0]), h2u(ac[1][1]), h2u(ac[1][2]), h2u(ac[1][3]));
        *(uint4*)(row + 256) = make_uint4(h2u(ac[2][0]), h2u(ac[2][1]), h2u(ac[2][2]), h2u(ac[2][3]));
    }
}

// ============================================================================
// mlp_gemm: y[m,o] = relu(sum_{ki<384} agg[m,ki]*GT[o,ki] + b[o]) + BN stats.
// 64-row M-tile, K-step 64, double-buffered async global_load_lds staging
// (pre-swizzled global source, linear LDS dest, swizzled ds_read).
// ============================================================================
__global__ __launch_bounds__(256)
void mlp_gemm(const __fp16* __restrict__ agg, const __fp16* __restrict__ GT,
              float* __restrict__ out, int M,
              const float* __restrict__ bias, float* __restrict__ sbuf) {
    __shared__ char smem[49152];     // buf b: A at b*24576 (8KB), B at +8192 (16KB)
    const int m0 = blockIdx.x * 64;
    const int tid = threadIdx.x;
    const int wave = tid >> 6, lane = tid & 63;
    const int wm0 = wave * 16;
    const int lrow = lane & 15;
    const int kg = lane >> 4;          // 0..3
    const int srow = lane >> 3;        // 0..7
    const int schunk = lane & 7;       // 0..7

    auto STAGE = [&](int buf, int kc) {
        char* base = smem + buf * 24576;
        #pragma unroll
        for (int j = 0; j < 2; ++j) {
            const int rl = wave * 16 + j * 8 + srow;
            const int rg = min(m0 + rl, M - 1);
            gload16(agg + (size_t)rg * 384 + kc * 64 + ((schunk ^ (rl & 7)) << 3),
                    base + (wave * 16 + j * 8) * 128);
        }
        #pragma unroll
        for (int j = 0; j < 4; ++j) {
            const int rl = wave * 32 + j * 8 + srow;
            gload16(GT + (size_t)rl * 384 + kc * 64 + ((schunk ^ (rl & 7)) << 3),
                    base + 8192 + (wave * 32 + j * 8) * 128);
        }
    };

    f32x4 acc[8];
    #pragma unroll
    for (int b = 0; b < 8; ++b) acc[b] = (f32x4){0.f, 0.f, 0.f, 0.f};

    STAGE(0, 0);
    __syncthreads();

    for (int kc = 0; kc < 6; ++kc) {
        const int buf = kc & 1;
        if (kc < 5) STAGE(buf ^ 1, kc + 1);
        const char* Ab = smem + buf * 24576;
        const char* Bb = Ab + 8192;
        f16x8 afr[2];
        #pragma unroll
        for (int ks = 0; ks < 2; ++ks) {
            const int row = wm0 + lrow;
            afr[ks] = *(const f16x8*)(Ab + row * 128 + (((ks * 4 + kg) ^ (row & 7)) << 4));
        }
        #pragma unroll
        for (int nf = 0; nf < 8; ++nf) {
            #pragma unroll
            for (int ks = 0; ks < 2; ++ks) {
                const int row = nf * 16 + lrow;
                f16x8 bfr = *(const f16x8*)(Bb + row * 128 + (((ks * 4 + kg) ^ (row & 7)) << 4));
                acc[nf] = __builtin_amdgcn_mfma_f32_16x16x32_f16(afr[ks], bfr, acc[nf], 0, 0, 0);
            }
        }
        __syncthreads();
    }

    float s[8], s2[8], bv[8];
    #pragma unroll
    for (int nf = 0; nf < 8; ++nf) { s[nf] = 0.f; s2[nf] = 0.f; bv[nf] = bias[nf * 16 + lrow]; }
    #pragma unroll
    for (int nf = 0; nf < 8; ++nf)
        #pragma unroll
        for (int rg = 0; rg < 4; ++rg) {
            const int row = m0 + wm0 + kg * 4 + rg;
            if (row < M) {
                const float v = fmaxf(acc[nf][rg] + bv[nf], 0.f);
                out[(size_t)row * FEAT + nf * 16 + lrow] = v;
                s[nf] += v;
                s2[nf] = fmaf(v, v, s2[nf]);
            }
        }
    #pragma unroll
    for (int nf = 0; nf < 8; ++nf) {
        s[nf]  += __shfl_xor(s[nf], 16);  s[nf]  += __shfl_xor(s[nf], 32);
        s2[nf] += __shfl_xor(s2[nf], 16); s2[nf] += __shfl_xor(s2[nf], 32);
    }
    __syncthreads();
    float* red = (float*)smem;                // [4][256]
    if (lane < 16) {
        #pragma unroll
        for (int nf = 0; nf < 8; ++nf) {
            red[wave * 256 + nf * 16 + lane]       = s[nf];
            red[wave * 256 + 128 + nf * 16 + lane] = s2[nf];
        }
    }
    __syncthreads();
    if (tid < 128) {
        const float ss = red[tid] + red[256 + tid] + red[512 + tid] + red[768 + tid];
        const float qq = red[128 + tid] + red[384 + tid] + red[640 + tid] + red[896 + tid];
        float* sb = sbuf + (blockIdx.x & (NSHARD - 1)) * 256;
        atomicAdd(sb + tid, ss);
        atomicAdd(sb + FEAT + tid, qq);
    }
}

// ---- BN normalize (sums the 16 stat shards, derives scale/shift) ----
__global__ void normalize(float* __restrict__ y, const float* __restrict__ sbuf,
                          const float* __restrict__ gamma, const float* __restrict__ beta) {
    __shared__ float sc_s[FEAT], sh_s[FEAT];
    const int t = threadIdx.x;
    if (t < FEAT) {
        float ssum = 0.f, qsum = 0.f;
        #pragma unroll
        for (int sh = 0; sh < NSHARD; ++sh) {
            ssum += sbuf[sh * 256 + t];
            qsum += sbuf[sh * 256 + 128 + t];
        }
        const float mean = ssum / (float)N_NODES;
        const float var  = qsum / (float)N_NODES - mean * mean;
        const float sc   = gamma[t] * rsqrtf(var + BN_EPS);
        sc_s[t] = sc;
        sh_s[t] = beta[t] - mean * sc;
    }
    __syncthreads();
    const int idx = blockIdx.x * blockDim.x + t;
    const int o4 = (idx & 31) * 4;
    float4 v = *(float4*)(y + (size_t)idx * 4);
    const float4 sc = *(const float4*)(sc_s + o4);
    const float4 sh = *(const float4*)(sh_s + o4);
    v.x = fmaf(v.x, sc.x, sh.x);
    v.y = fmaf(v.y, sc.y, sh.y);
    v.z = fmaf(v.z, sc.z, sh.z);
    v.w = fmaf(v.w, sc.w, sh.w);
    *(float4*)(y + (size_t)idx * 4) = v;
}

extern "C" void kernel_launch(void* const* d_in, const int* in_sizes, int n_in,
                              void* d_out, int out_size, void* d_ws, size_t ws_size,
                              hipStream_t stream) {
    const float* feature = (const float*)d_in[0];
    const float* coords  = (const float*)d_in[1];
    const int*   src     = (const int*)d_in[2];
    const int*   dst     = (const int*)d_in[3];
    const int*   order   = (const int*)d_in[4];
    const float* linear  = (const float*)d_in[5];
    const float* attW    = (const float*)d_in[6];
    const float* mlp_w   = (const float*)d_in[7];
    const float* mlp_b   = (const float*)d_in[8];
    const float* gamma   = (const float*)d_in[9];
    const float* beta    = (const float*)d_in[10];
    float* out = (float*)d_out;

    char* p = (char*)d_ws;
    __fp16* fh           = (__fp16*)p;  p += (size_t)N_NODES * FEAT * 2;   // 12.8 MB
    __fp16* agg          = (__fp16*)p;  p += (size_t)N_NODES * 384 * 2;    // 38.4 MB
    __fp16* GT           = (__fp16*)p;  p += (size_t)FEAT * 384 * 2;       // 98 KB
    float4* pk           = (float4*)p;  p += (size_t)N_NODES * 32;         // 1.6 MB
    int*   sord_p        = (int*)p;     p += (size_t)E_EDGES * 4;          // 3.2 MB
    int2*  bbuf          = (int2*)p;    p += (size_t)NBUK * BCAP * 8;      // 8.0 MB
    int*   cnt           = (int*)p;     p += 200064;
    float* sbuf          = (float*)p;   p += NSHARD * 256 * 4;             // 16 KB
    int*   gcur          = (int*)p;     p += 1024;   // memset covers cnt+sbuf+gcur
    int*   rowptr        = (int*)p;     p += 200064;
    int*   cursor        = (int*)p;     p += 200064;
    int*   bsum          = (int*)p;     p += 256;
    int*   boff          = (int*)p;     p += 256;

    hipMemsetAsync(cnt, 0, 200064 + NSHARD * 256 * 4 + 1024, stream);

    const int NWB = (N_NODES * 64) / 256;         // 12500
    const int MB  = (N_NODES + 63) / 64;          // 782
    const int AB  = (E_EDGES + 2047) / 2048;      // 391

    gprep<<<FEAT, FEAT, 0, stream>>>(mlp_w, linear, GT);
    g_cast<<<NWB, 256, 0, stream>>>(feature, coords, attW, fh, pk);

    bucketA<<<AB, 256, 0, stream>>>(src, dst, order, cnt, gcur, bbuf);
    scan1<<<NB1, 256, 0, stream>>>(cnt, rowptr, bsum);
    scan2<<<1, 64, 0, stream>>>(bsum, boff, rowptr);
    scan3<<<(N_NODES + 255) / 256, 256, 0, stream>>>(rowptr, cursor, boff);
    bucketB<<<NBUK * 8, 256, 0, stream>>>(gcur, bbuf, cursor, sord_p);

    segagg<<<NWB, 256, 0, stream>>>(pk, sord_p, rowptr, fh, agg);

    mlp_gemm<<<MB, 256, 0, stream>>>(agg, GT, out, N_NODES, mlp_b, sbuf);
    normalize<<<(N_NODES * 32) / 256, 256, 0, stream>>>(out, sbuf, gamma, beta);
}